// Round 4
// baseline (578.336 us; speedup 1.0000x reference)
//
#include <hip/hip_runtime.h>
#include <hip/hip_bf16.h>

constexpr int Ej  = 294912;  // total edges
constexpr int EPG = 1152;    // edges per graph
constexpr int WC2 = 144;     // fused-GEMM cols per head: A64 | V64 | r8:8 | cD | cS | pad6
constexpr int SPF = 132;     // scores fp32 row stride (floats); bf16 Wmat row lives at hw d*264
constexpr int HBS = 72;      // hB / A-matrix bf16 row stride (halfwords)
constexpr int VTS = 136;     // Vt bf16 row stride (halfwords)

typedef __attribute__((ext_vector_type(8))) short short8;   // 8 bf16 (MFMA A/B frag)
typedef __attribute__((ext_vector_type(4))) float f32x4;    // MFMA C/D frag

// fp32 -> bf16 bits, round-to-nearest-even
__device__ __forceinline__ unsigned short f2bf(float f) {
  unsigned u = __float_as_uint(f);
  u += 0x7FFFu + ((u >> 16) & 1u);
  return (unsigned short)(u >> 16);
}
__device__ __forceinline__ float bf2f(unsigned short b) {
  return __uint_as_float(((unsigned)b) << 16);
}
// DPP helpers: reductions within aligned 8-lane groups, pure VALU (no LDS pipe).
template <int CTRL>
__device__ __forceinline__ float dppf(float x) {
  return __int_as_float(__builtin_amdgcn_update_dpp(0, __float_as_int(x), CTRL, 0xf, 0xf, true));
}
// 0xB1 = quad_perm xor1, 0x4E = quad_perm xor2, 0x141 = row_half_mirror (i<->7-i in 8)
__device__ __forceinline__ float grp8_sum(float x) {
  x += dppf<0xB1>(x); x += dppf<0x4E>(x); x += dppf<0x141>(x); return x;
}
__device__ __forceinline__ float grp8_max(float x) {
  x = fmaxf(x, dppf<0xB1>(x)); x = fmaxf(x, dppf<0x4E>(x)); x = fmaxf(x, dppf<0x141>(x));
  return x;
}
// 64-lane sum via DPP. Result valid in lane 63.
__device__ __forceinline__ float wave_red_sum(float x) {
  x += __int_as_float(__builtin_amdgcn_update_dpp(0, __float_as_int(x), 0x111, 0xf, 0xf, true));
  x += __int_as_float(__builtin_amdgcn_update_dpp(0, __float_as_int(x), 0x112, 0xf, 0xf, true));
  x += __int_as_float(__builtin_amdgcn_update_dpp(0, __float_as_int(x), 0x114, 0xf, 0xf, true));
  x += __int_as_float(__builtin_amdgcn_update_dpp(0, __float_as_int(x), 0x118, 0xf, 0xf, true));
  x += __int_as_float(__builtin_amdgcn_update_dpp(0, __float_as_int(x), 0x142, 0xf, 0xf, true));
  x += __int_as_float(__builtin_amdgcn_update_dpp(0, __float_as_int(x), 0x143, 0xf, 0xf, true));
  return x;
}

// G[l][h][a][c] = sum_d W_edge[a,d]*We_l[d][h64+c];  bb[l][h][c] = be + b_edge@We
__global__ void k_prep2(const float* __restrict__ We, const float* __restrict__ be,
                        const float* __restrict__ W_edge, const float* __restrict__ b_edge,
                        float* __restrict__ G, float* __restrict__ bb) {
  int tid = blockIdx.x * 256 + threadIdx.x;  // 8192 + 1024
  if (tid < 8192) {
    int l = tid >> 11, rem = tid & 2047;
    int hh = rem >> 9, a = (rem >> 6) & 7, c = rem & 63;
    float acc = 0.f;
#pragma unroll 8
    for (int d = 0; d < 64; ++d)
      acc += W_edge[a * 64 + d] * We[l * 16384 + d * 256 + hh * 64 + c];
    G[tid] = acc;
  } else if (tid < 9216) {
    int t = tid - 8192;
    int l = t >> 8, rem = t & 255;
    int hh = rem >> 6, c = rem & 63;
    float acc = be[l * 256 + hh * 64 + c];
#pragma unroll 8
    for (int d = 0; d < 64; ++d)
      acc += b_edge[d] * We[l * 16384 + d * 256 + hh * 64 + c];
    bb[t] = acc;
  }
}

// WcatT [lh][col][kk] bf16 + bcatT fp32.  (see r1-r3 for column semantics)
__global__ void __launch_bounds__(256) k_prepW(
    const float* __restrict__ Wq, const float* __restrict__ bq,
    const float* __restrict__ Wk, const float* __restrict__ bk,
    const float* __restrict__ Wv, const float* __restrict__ bv,
    const float* __restrict__ Gbuf, const float* __restrict__ bbuf,
    unsigned short* __restrict__ WcatT, float* __restrict__ bcatT) {
  int t = blockIdx.x * 256 + threadIdx.x;  // 16*144*64
  if (t >= 16 * WC2 * 64) return;
  int kk = t & 63;
  int col = (t >> 6) % WC2;
  int lh = t / (WC2 * 64);
  int h = lh & 3, l = lh >> 2;
  const float* Wq_l = Wq + l * 16384;
  const float* Wk_l = Wk + l * 16384;
  const float* bq_l = bq + l * 256;
  const float* bk_l = bk + l * 256;
  float w = 0.f, bias = 0.f;
  if (col < 64) {
    float s = 0.f;
#pragma unroll 8
    for (int i = 0; i < 64; ++i)
      s += Wq_l[kk * 256 + h * 64 + i] * Wk_l[col * 256 + h * 64 + i];
    w = 0.125f * s;
  } else if (col < 128) {
    int j = col - 64;
    w = Wv[l * 16384 + kk * 256 + h * 64 + j];
    bias = bv[l * 256 + h * 64 + j];
  } else if (col < 136) {
    int a = col - 128;
    const float* Grow = Gbuf + l * 2048 + h * 512 + a * 64;
    float s = 0.f, sb = 0.f;
#pragma unroll 8
    for (int i = 0; i < 64; ++i) {
      s  += Wq_l[kk * 256 + h * 64 + i] * Grow[i];
      sb += bq_l[h * 64 + i] * Grow[i];
    }
    w = 0.125f * s; bias = 0.125f * sb;
  } else if (col == 136) {
    float s = 0.f, sb = 0.f;
#pragma unroll 8
    for (int i = 0; i < 64; ++i) {
      float bkb = bk_l[h * 64 + i] + bbuf[l * 256 + h * 64 + i];
      s  += Wq_l[kk * 256 + h * 64 + i] * bkb;
      sb += bq_l[h * 64 + i] * bkb;
    }
    w = 0.125f * s; bias = 0.125f * sb;
  } else if (col == 137) {
    float s = 0.f;
#pragma unroll 8
    for (int i = 0; i < 64; ++i)
      s += Wk_l[kk * 256 + h * 64 + i] * bq_l[h * 64 + i];
    w = 0.125f * s;
  }
  WcatT[(size_t)(lh * WC2 + col) * 64 + kk] = f2bf(w);
  if (kk == 0) bcatT[lh * WC2 + col] = bias;
}

// Counting sort of each graph's edges by key = dst*128+src. Emits sortedSR (src | duprank<<8),
// sortedEA (edge_attr reordered), offs[g][129] (per-dst segment offsets).
__global__ void __launch_bounds__(256) k_sort(const int* __restrict__ ei,
                                              const float* __restrict__ edge_attr,
                                              int* __restrict__ sortedSR,
                                              float* __restrict__ sortedEA,
                                              int* __restrict__ offs) {
  __shared__ unsigned hist[16384];    // 64 KB
  __shared__ unsigned cursor[16384];  // 64 KB
  __shared__ unsigned csum[256];
  int g = blockIdx.x, tid = threadIdx.x;
#pragma unroll
  for (int i = 0; i < 64; ++i) { hist[tid * 64 + i] = 0u; cursor[tid * 64 + i] = 0u; }
  __syncthreads();
  for (int e = tid; e < EPG; e += 256) {
    int s = ei[g * EPG + e] - g * 128;
    int d = ei[Ej + g * EPG + e] - g * 128;
    atomicAdd(&hist[d * 128 + s], 1u);
  }
  __syncthreads();
  // exclusive scan (chunk-serial + single-thread chunk scan)
  unsigned acc = 0;
  int base = tid * 64;
#pragma unroll
  for (int i = 0; i < 64; ++i) { unsigned t = hist[base + i]; hist[base + i] = acc; acc += t; }
  csum[tid] = acc;
  __syncthreads();
  if (tid == 0) {
    unsigned run = 0;
    for (int j = 0; j < 256; ++j) { unsigned t = csum[j]; csum[j] = run; run += t; }
  }
  __syncthreads();
  unsigned off = csum[tid];
#pragma unroll
  for (int i = 0; i < 64; ++i) hist[base + i] += off;
  __syncthreads();
  if (tid < 128) offs[g * 129 + tid] = (int)hist[tid * 128];
  if (tid == 0) offs[g * 129 + 128] = EPG;
  // scatter (order within identical (dst,src) irrelevant; rank via cursor)
  for (int e = tid; e < EPG; e += 256) {
    int s = ei[g * EPG + e] - g * 128;
    int d = ei[Ej + g * EPG + e] - g * 128;
    int key = d * 128 + s;
    unsigned r = atomicAdd(&cursor[key], 1u);
    unsigned pos = hist[key] + r;
    sortedSR[g * EPG + pos] = s | ((int)min(r, 3u) << 8);
    const float4* ep = (const float4*)(edge_attr + ((size_t)g * EPG + e) * 8);
    float4* op = (float4*)(sortedEA + ((size_t)g * EPG + pos) * 8);
    op[0] = ep[0]; op[1] = ep[1];
  }
}

// One block per graph, 1024 threads (16 waves, 4/SIMD). 4 barriers per head:
// P0 (qkv GEMM, WT from global) | P1 (scores MFMA) | PD (per-dst softmax via DPP, no atomics,
// Wmat bf16 written into each score row's own footprint) | P5 (Wmat@Vt MFMA + epilogue).
// LDS 152576 B -> 1 block/CU.
__global__ void __launch_bounds__(1024, 4) k_fused(
    const float* __restrict__ x, const float* __restrict__ W_node, const float* __restrict__ b_node,
    const unsigned short* __restrict__ WcatT, const float* __restrict__ bcatT,
    const int* __restrict__ sortedSR, const float* __restrict__ sortedEA,
    const int* __restrict__ offs,
    const float* __restrict__ Gbuf, const float* __restrict__ bbuf,
    const float* __restrict__ Wskip, const float* __restrict__ bskip,
    const float* __restrict__ Wd, const float* __restrict__ bd,
    const float* __restrict__ Wo, const float* __restrict__ bo,
    float* __restrict__ out) {
  __shared__ float SS[128 * SPF];           // 67584 B: scores fp32 / Wmat bf16 (in-row) / Wskip
  __shared__ float h32[128 * 68];           // 34816 B: resident fp32 h
  __shared__ unsigned short hB[128 * HBS];  // 18432 B: bf16 h
  __shared__ unsigned short AV[128 * HBS];  // 18432 B: A-matrix (P0-P1) then Vt 64xVTS (PD-P5)
  __shared__ float r8L[128 * 8];            // 4096
  __shared__ float t8L[128 * 9];            // 4608
  __shared__ float sL[128];                 // 512
  __shared__ float cDL[128];                // 512
  __shared__ float cSL[128];                // 512
  __shared__ float GhL[512];                // 2048
  __shared__ float vembL[256];              // 1024

  int g = blockIdx.x, tid = threadIdx.x;
  int lane = tid & 63, m16 = lane & 15, quad = lane >> 4, wv = tid >> 6;  // wv 0..15
  const int strip = wv >> 1, ch = wv & 1;
  const int m0 = strip * 16;

  // node encoder -> h32
  for (int idx = tid; idx < 8192; idx += 1024) {
    int n = idx >> 6, c = idx & 63;
    const float* xr = x + (size_t)(g * 128 + n) * 16;
    float acc = b_node[c];
#pragma unroll
    for (int d = 0; d < 16; ++d) acc += xr[d] * W_node[d * 64 + c];
    h32[n * 68 + c] = acc;
  }

  // per-dst segment (8 lanes per dst)
  const int dD = tid >> 3, sub = tid & 7;
  const int ofsD = offs[g * 129 + dD];
  const int cntD = offs[g * 129 + dD + 1] - ofsD;
  const int dsw = (dD & 7) << 4;  // XOR swizzle (float idx for scores, hw idx for Wmat)
  const int gE = g * EPG;
  __syncthreads();

  for (int l = 0; l < 4; ++l) {
    // ---- stage hB = bf16(h32)
    {
      int row = tid >> 3, c8 = tid & 7;
      const float* hr = &h32[row * 68 + c8 * 8];
      float4 a0 = *(const float4*)hr, a1 = *(const float4*)(hr + 4);
      uint4 hp;
      hp.x = f2bf(a0.x) | ((unsigned)f2bf(a0.y) << 16);
      hp.y = f2bf(a0.z) | ((unsigned)f2bf(a0.w) << 16);
      hp.z = f2bf(a1.x) | ((unsigned)f2bf(a1.y) << 16);
      hp.w = f2bf(a1.z) | ((unsigned)f2bf(a1.w) << 16);
      *(uint4*)&hB[row * HBS + c8 * 8] = hp;
    }
    __syncthreads();

    f32x4 accP5_0 = {0.f, 0.f, 0.f, 0.f};
    f32x4 accP5_1 = {0.f, 0.f, 0.f, 0.f};
    float4 wskL;

    for (int h = 0; h < 4; ++h) {
      const int lh = l * 4 + h;
      // ---- P0: qkv GEMM. ch0: A-tiles 0..3 + special; ch1: V-tiles. WT direct from global.
      const float* bcTl = bcatT + (size_t)lh * WC2;
      const unsigned short* WTg = WcatT + (size_t)lh * WC2 * 64;
      f32x4 vf0, vf1, vf2, vf3;
      {
        if (tid < 512) GhL[tid] = Gbuf[l * 2048 + h * 512 + tid];
        const short8 a0 = *(const short8*)&hB[(m0 + m16) * HBS + quad * 8];
        const short8 a1 = *(const short8*)&hB[(m0 + m16) * HBS + 32 + quad * 8];
#pragma unroll
        for (int j = 0; j < 4; ++j) {
          int n0 = (ch * 4 + j) * 16;
          const unsigned short* wb = WTg + (size_t)(n0 + m16) * 64 + quad * 8;
          const short8 b0 = *(const short8*)wb;
          const short8 b1 = *(const short8*)(wb + 32);
          float bias = bcTl[n0 + m16];
          f32x4 acc = {bias, bias, bias, bias};
          acc = __builtin_amdgcn_mfma_f32_16x16x32_bf16(a0, b0, acc, 0, 0, 0);
          acc = __builtin_amdgcn_mfma_f32_16x16x32_bf16(a1, b1, acc, 0, 0, 0);
          if (ch == 0) {
#pragma unroll
            for (int r = 0; r < 4; ++r)
              AV[(m0 + quad * 4 + r) * HBS + n0 + m16] = f2bf(acc[r]);
          } else {
            if (j == 0) vf0 = acc;
            else if (j == 1) vf1 = acc;
            else if (j == 2) vf2 = acc;
            else vf3 = acc;
          }
        }
        if (ch == 0) {  // special tile n0=128: r8 | cD | cS
          const unsigned short* wb = WTg + (size_t)(128 + m16) * 64 + quad * 8;
          const short8 b0 = *(const short8*)wb;
          const short8 b1 = *(const short8*)(wb + 32);
          float bias = bcTl[128 + m16];
          f32x4 acc = {bias, bias, bias, bias};
          acc = __builtin_amdgcn_mfma_f32_16x16x32_bf16(a0, b0, acc, 0, 0, 0);
          acc = __builtin_amdgcn_mfma_f32_16x16x32_bf16(a1, b1, acc, 0, 0, 0);
          if (m16 < 8) {
#pragma unroll
            for (int r = 0; r < 4; ++r) r8L[(m0 + quad * 4 + r) * 8 + m16] = acc[r];
          } else if (m16 == 8) {
#pragma unroll
            for (int r = 0; r < 4; ++r) cDL[m0 + quad * 4 + r] = acc[r];
          } else if (m16 == 9) {
#pragma unroll
            for (int r = 0; r < 4; ++r) cSL[m0 + quad * 4 + r] = acc[r];
          }
        }
      }
      __syncthreads();

      // ---- P1: scores = A @ hB^T -> SS fp32, col XOR-swizzled per row
      {
        const short8 a0 = *(const short8*)&AV[(m0 + m16) * HBS + quad * 8];
        const short8 a1 = *(const short8*)&AV[(m0 + m16) * HBS + 32 + quad * 8];
#pragma unroll
        for (int t = 0; t < 4; ++t) {
          int src0 = ch * 64 + t * 16;
          const short8 b0 = *(const short8*)&hB[(src0 + m16) * HBS + quad * 8];
          const short8 b1 = *(const short8*)&hB[(src0 + m16) * HBS + 32 + quad * 8];
          f32x4 acc = {0.f, 0.f, 0.f, 0.f};
          acc = __builtin_amdgcn_mfma_f32_16x16x32_bf16(a0, b0, acc, 0, 0, 0);
          acc = __builtin_amdgcn_mfma_f32_16x16x32_bf16(a1, b1, acc, 0, 0, 0);
#pragma unroll
          for (int r = 0; r < 4; ++r) {
            int row = m0 + quad * 4 + r;
            SS[row * SPF + ((src0 + m16) ^ ((row & 7) << 4))] = acc[r];
          }
        }
      }
      __syncthreads();

      // ---- PD: V-deposit; per-dst softmax (DPP reductions, no atomics); zero+scatter Wmat bf16
      {
        if (ch == 1) {  // deposit V frags -> Vt (transposed bf16)
#pragma unroll
          for (int r = 0; r < 4; ++r) AV[(m16) * VTS + m0 + quad * 4 + r] = f2bf(vf0[r]);
#pragma unroll
          for (int r = 0; r < 4; ++r) AV[(16 + m16) * VTS + m0 + quad * 4 + r] = f2bf(vf1[r]);
#pragma unroll
          for (int r = 0; r < 4; ++r) AV[(32 + m16) * VTS + m0 + quad * 4 + r] = f2bf(vf2[r]);
#pragma unroll
          for (int r = 0; r < 4; ++r) AV[(48 + m16) * VTS + m0 + quad * 4 + r] = f2bf(vf3[r]);
        }
        // load this thread's edges (<=5, predicated, static)
        int sr[5];
        float4 e0[5], e1[5];
#pragma unroll
        for (int it = 0; it < 5; ++it) {
          int p = sub + it * 8;
          bool v = p < cntD;
          sr[it] = -1;
          e0[it] = make_float4(0.f, 0.f, 0.f, 0.f);
          e1[it] = e0[it];
          if (v) {
            int e = gE + ofsD + p;
            sr[it] = sortedSR[e];
            e0[it] = *(const float4*)(sortedEA + (size_t)e * 8);
            e1[it] = *(const float4*)(sortedEA + (size_t)e * 8 + 4);
          }
        }
        float r8r[8];
#pragma unroll
        for (int k = 0; k < 8; ++k) r8r[k] = r8L[dD * 8 + k];
        float cD = cDL[dD];
        float al[5];
#pragma unroll
        for (int it = 0; it < 5; ++it) {
          float a = -3.4e38f;
          if (sr[it] >= 0) {
            int src = sr[it] & 127;
            a = SS[dD * SPF + (src ^ dsw)] + cD + cSL[src]
              + e0[it].x * r8r[0] + e0[it].y * r8r[1] + e0[it].z * r8r[2] + e0[it].w * r8r[3]
              + e1[it].x * r8r[4] + e1[it].y * r8r[5] + e1[it].z * r8r[6] + e1[it].w * r8r[7];
          }
          al[it] = a;
        }
        float m = fmaxf(fmaxf(fmaxf(al[0], al[1]), fmaxf(al[2], al[3])), al[4]);
        m = grp8_max(m);
        float s = 0.f;
#pragma unroll
        for (int it = 0; it < 5; ++it) {
          float e = (sr[it] >= 0) ? expf(al[it] - m) : 0.f;
          al[it] = e;
          s += e;
        }
        s = grp8_sum(s);
        float inv = 1.f / fmaxf(s, 1e-16f);
        float t8p[8] = {0.f, 0.f, 0.f, 0.f, 0.f, 0.f, 0.f, 0.f};
#pragma unroll
        for (int it = 0; it < 5; ++it) {
          float w = al[it] * inv;
          al[it] = w;
          t8p[0] += w * e0[it].x; t8p[1] += w * e0[it].y;
          t8p[2] += w * e0[it].z; t8p[3] += w * e0[it].w;
          t8p[4] += w * e1[it].x; t8p[5] += w * e1[it].y;
          t8p[6] += w * e1[it].z; t8p[7] += w * e1[it].w;
        }
#pragma unroll
        for (int k = 0; k < 8; ++k) t8p[k] = grp8_sum(t8p[k]);
        if (sub == 0) {
#pragma unroll
          for (int k = 0; k < 8; ++k) t8L[dD * 9 + k] = t8p[k];
          sL[dD] = s;
        }
        // zero this row's Wmat footprint, then scatter w (same wave; LDS in-order)
        __builtin_amdgcn_sched_barrier(0);
        unsigned short* Wu = (unsigned short*)SS;
        int rowb = dD * 264;
        int z0 = (sub * 16) ^ dsw;
        uint4 zz = make_uint4(0u, 0u, 0u, 0u);
        *(uint4*)&Wu[rowb + z0] = zz;
        *(uint4*)&Wu[rowb + z0 + 8] = zz;
        __builtin_amdgcn_sched_barrier(0);
        bool anyDup = false;
#pragma unroll
        for (int it = 0; it < 5; ++it) {
          if (sr[it] >= 0) {
            int rk = (sr[it] >> 8) & 3;
            anyDup |= (rk != 0);
            if (rk == 0) Wu[rowb + ((sr[it] & 127) ^ dsw)] = f2bf(al[it]);
          }
        }
        if (__any(anyDup)) {  // rare duplicate (dst,src) edges: rank-ordered accumulate
#pragma unroll
          for (int rk = 1; rk < 4; ++rk) {
            __builtin_amdgcn_sched_barrier(0);
#pragma unroll
            for (int it = 0; it < 5; ++it) {
              if (sr[it] >= 0 && (((sr[it] >> 8) & 3) == rk)) {
                int slot = rowb + ((sr[it] & 127) ^ dsw);
                Wu[slot] = f2bf(bf2f(Wu[slot]) + al[it]);
              }
            }
          }
        }
      }
      __syncthreads();

      // ---- P5: accP5 += Wmat@Vt (MFMA) + t8@G + (s>0)*bb
      {
        if (h == 3) wskL = ((const float4*)(Wskip + (size_t)l * 4096))[tid];
        const unsigned short* Wu = (const unsigned short*)SS;
        int row0 = m0 + m16;
        short8 a_[4];
#pragma unroll
        for (int ks = 0; ks < 4; ++ks)
          a_[ks] = *(const short8*)&Wu[row0 * 264 + (((ks * 32) + quad * 8) ^ ((row0 & 7) << 4))];
#pragma unroll
        for (int t2 = 0; t2 < 2; ++t2) {
          int c0 = ch * 32 + t2 * 16;
          f32x4 acc = (t2 == 0) ? accP5_0 : accP5_1;
#pragma unroll
          for (int ks = 0; ks < 4; ++ks) {
            const short8 b = *(const short8*)&AV[(c0 + m16) * VTS + ks * 32 + quad * 8];
            acc = __builtin_amdgcn_mfma_f32_16x16x32_bf16(a_[ks], b, acc, 0, 0, 0);
          }
          int col = c0 + m16;
          float bbv = bbuf[l * 256 + h * 64 + col];
          float gcol[8];
#pragma unroll
          for (int a8 = 0; a8 < 8; ++a8) gcol[a8] = GhL[a8 * 64 + col];
#pragma unroll
          for (int r = 0; r < 4; ++r) {
            int row = m0 + quad * 4 + r;
            float add = (sL[row] > 0.f) ? bbv : 0.f;
#pragma unroll
            for (int a8 = 0; a8 < 8; ++a8) add += t8L[row * 9 + a8] * gcol[a8];
            acc[r] += add;
          }
          if (t2 == 0) accP5_0 = acc; else accP5_1 = acc;
        }
      }
      __syncthreads();
    }  // heads

    // ---- update: out = 0.25*acc + h@Wskip+bskip ; vemb ; h += out
    *(float4*)&SS[tid * 4] = wskL;  // Wskip_l -> SS[0..4096)
    __syncthreads();
    {
      float sk0[4], sk1[4];
#pragma unroll
      for (int t2 = 0; t2 < 2; ++t2) {
        int col = ch * 32 + t2 * 16 + m16;
        float bsv = bskip[l * 64 + col];
#pragma unroll
        for (int r = 0; r < 4; ++r) {
          int row = m0 + quad * 4 + r;
          float s = bsv;
#pragma unroll 8
          for (int d = 0; d < 64; ++d) s += h32[row * 68 + d] * SS[d * 64 + col];
          if (t2 == 0) sk0[r] = s; else sk1[r] = s;
        }
      }
      __syncthreads();  // all h32 reads done before in-place writes
#pragma unroll
      for (int t2 = 0; t2 < 2; ++t2) {
        int col = ch * 32 + t2 * 16 + m16;
#pragma unroll
        for (int r = 0; r < 4; ++r) {
          int row = m0 + quad * 4 + r;
          float av = (t2 == 0) ? accP5_0[r] : accP5_1[r];
          float outv = av * 0.25f + ((t2 == 0) ? sk0[r] : sk1[r]);
          float hnew = outv + h32[row * 68 + col];
          h32[row * 68 + col] = hnew;
          if (row == 127) vembL[l * 64 + col] = outv;
        }
      }
    }
    __syncthreads();
  }  // layers

  // ---- head: pool = vemb @ W_down + b_down; out = sigmoid(pool @ W_out + b_out)
  {
    float part = 0.f;
#pragma unroll
    for (int j2 = 0; j2 < 16; ++j2) {
      int j = wv * 16 + j2;
      part += vembL[j] * Wd[j * 64 + lane];
    }
    SS[wv * 64 + lane] = part;
    __syncthreads();
    if (wv == 0) {
      float acc = bd[lane];
#pragma unroll
      for (int w2 = 0; w2 < 16; ++w2) acc += SS[w2 * 64 + lane];
      float p = acc * Wo[lane];
      p = wave_red_sum(p);
      if (lane == 63) out[g] = 1.f / (1.f + expf(-(p + bo[0])));
    }
  }
}

extern "C" void kernel_launch(void* const* d_in, const int* in_sizes, int n_in,
                              void* d_out, int out_size, void* d_ws, size_t ws_size,
                              hipStream_t stream) {
  const float* x         = (const float*)d_in[0];
  const float* edge_attr = (const float*)d_in[1];
  const int*   ei        = (const int*)d_in[2];
  const float* W_node = (const float*)d_in[4];
  const float* b_node = (const float*)d_in[5];
  const float* W_edge = (const float*)d_in[6];
  const float* b_edge = (const float*)d_in[7];
  const float* Wq = (const float*)d_in[8];
  const float* bq = (const float*)d_in[9];
  const float* Wk = (const float*)d_in[10];
  const float* bk = (const float*)d_in[11];
  const float* Wv = (const float*)d_in[12];
  const float* bv = (const float*)d_in[13];
  const float* We = (const float*)d_in[14];
  const float* be = (const float*)d_in[15];
  const float* Wskip = (const float*)d_in[16];
  const float* bskip = (const float*)d_in[17];
  const float* W_down = (const float*)d_in[18];
  const float* b_down = (const float*)d_in[19];
  const float* W_out  = (const float*)d_in[20];
  const float* b_out  = (const float*)d_in[21];
  float* out = (float*)d_out;

  // workspace carve (~11.2 MB)
  float* p = (float*)d_ws;
  float* Gbuf  = p; p += 8192;
  float* bbuf  = p; p += 1024;
  float* bcatT = p; p += 16 * WC2;                  // 2304 floats
  unsigned short* WcatT = (unsigned short*)p; p += 16 * WC2 * 64 / 2;  // bf16, 294912 B
  int* offsB   = (int*)p; p += 256 * 129;           // 132 KB
  int* sortedSR = (int*)p; p += Ej;                 // 1.18 MB
  float* sortedEA = p; p += (size_t)Ej * 8;         // 9.44 MB

  k_prep2<<<36, 256, 0, stream>>>(We, be, W_edge, b_edge, Gbuf, bbuf);
  k_prepW<<<(16 * WC2 * 64) / 256, 256, 0, stream>>>(Wq, bq, Wk, bk, Wv, bv, Gbuf, bbuf,
                                                     WcatT, bcatT);
  k_sort<<<256, 256, 0, stream>>>(ei, edge_attr, sortedSR, sortedEA, offsB);
  k_fused<<<256, 1024, 0, stream>>>(x, W_node, b_node, WcatT, bcatT,
                                    sortedSR, sortedEA, offsB,
                                    Gbuf, bbuf, Wskip, bskip, W_down, b_down, W_out, b_out,
                                    out);
}